// Round 1
// baseline (2252.527 us; speedup 1.0000x reference)
//
#include <hip/hip_runtime.h>
#include <hip/hip_fp16.h>
#include <cmath>

#define NN 20000
#define EE 500000
#define GG 64
#define TS 4096
#define EPS 1e-5f

__device__ __forceinline__ float softplus_f(float x) {
    return fmaxf(x, 0.f) + log1pf(__expf(-fabsf(x)));
}

// gaussian table: g[s][k] = exp(coeff*(d_s - o_k)^2)
__global__ void k_gtab(float* __restrict__ g) {
    int i = blockIdx.x * 256 + threadIdx.x;
    if (i >= TS * 100) return;
    int s = i / 100, k = i - 100 * s;
    float d = s * (6.0f / 4095.0f);
    float o = k * (6.0f / 99.0f);
    float step = 6.0f / 99.0f;
    float coeff = -0.5f / (step * step);
    float df = d - o;
    g[i] = __expf(coeff * df * df);
}

// T[l][s][c] = conv_b[l][c] + sum_k g[s][k] * conv_W[l][128+k][c]   (fp16)
__global__ void k_build_T(const float* __restrict__ g, const float* __restrict__ convW,
                          const float* __restrict__ convB, __half* __restrict__ T) {
    int c = threadIdx.x;            // 128
    int s = blockIdx.x;             // TS
    int l = blockIdx.y;             // 6
    const float* gr = g + (size_t)s * 100;
    const float* w = convW + ((size_t)l * 228 + 128) * 128 + c;
    float acc = convB[l * 128 + c];
#pragma unroll 4
    for (int k = 0; k < 100; k++) acc += gr[k] * w[k * 128];
    T[((size_t)l * TS + s) * 128 + c] = __float2half(acc);
}

// x[n][c] = nuc_b[c] + sum_k emb[an[n]][k] * nucW[k][c]
__global__ void k_embed(const int* __restrict__ an, const float* __restrict__ emb,
                        const float* __restrict__ W, const float* __restrict__ b,
                        float* __restrict__ x) {
    int c = threadIdx.x & 63, nl = threadIdx.x >> 6;
    int n = blockIdx.x * 4 + nl;
    if (n >= NN) return;
    const float* e = emb + (size_t)an[n] * 92;
    float acc = b[c];
#pragma unroll 4
    for (int k = 0; k < 92; k++) acc += e[k] * W[k * 64 + c];
    x[(size_t)n * 64 + c] = acc;
}

__global__ void k_hist(const int* __restrict__ dst, int* __restrict__ counts) {
    int e = blockIdx.x * 256 + threadIdx.x;
    if (e < EE) atomicAdd(&counts[dst[e]], 1);
}

__global__ void k_scan(const int* __restrict__ counts, int* __restrict__ rp) {
    __shared__ int buf[1024];
    __shared__ int carry;
    int tid = threadIdx.x;
    if (tid == 0) { carry = 0; rp[0] = 0; }
    __syncthreads();
    for (int base = 0; base < NN; base += 1024) {
        int i = base + tid;
        int val = (i < NN) ? counts[i] : 0;
        buf[tid] = val;
        __syncthreads();
        for (int off = 1; off < 1024; off <<= 1) {
            int t = (tid >= off) ? buf[tid - off] : 0;
            __syncthreads();
            buf[tid] += t;
            __syncthreads();
        }
        if (i < NN) rp[i + 1] = carry + buf[tid];
        __syncthreads();
        if (tid == 0) carry += buf[1023];
        __syncthreads();
    }
}

__global__ void k_scatter(const int* __restrict__ dst, const int* __restrict__ rp,
                          int* __restrict__ cursor, int* __restrict__ perm) {
    int e = blockIdx.x * 256 + threadIdx.x;
    if (e < EE) {
        int d = dst[e];
        int p = atomicAdd(&cursor[d], 1);
        perm[rp[d] + p] = e;
    }
}

// u = x@W[0:64], v = x@W[64:128]; one wave per node, lane owns 4 output cols
__global__ void k_uv(const float* __restrict__ x, const float* __restrict__ convW,
                     int l, __half* __restrict__ u, __half* __restrict__ v) {
    int lane = threadIdx.x & 63;
    int n = blockIdx.x * 4 + (threadIdx.x >> 6);
    if (n >= NN) return;
    float xv = x[(size_t)n * 64 + lane];
    bool isu = lane < 32;
    int col = isu ? lane * 4 : lane * 4 - 128;
    const float* wbase = convW + (size_t)l * 228 * 128 + (isu ? 0 : 64 * 128) + col;
    float4 acc = {0.f, 0.f, 0.f, 0.f};
#pragma unroll 8
    for (int k = 0; k < 64; k++) {
        float xk = __shfl(xv, k, 64);
        float4 w = *(const float4*)(wbase + (size_t)k * 128);
        acc.x += xk * w.x; acc.y += xk * w.y; acc.z += xk * w.z; acc.w += xk * w.w;
    }
    __half* out = isu ? u : v;
    __half2* o2 = (__half2*)(out + (size_t)n * 128 + col);
    o2[0] = __floats2half2_rn(acc.x, acc.y);
    o2[1] = __floats2half2_rn(acc.z, acc.w);
}

// pass A: per-channel sum / sumsq of z = u[dst]+v[src]+lerp(T,d)
__global__ void k_stats(const __half2* __restrict__ u2, const __half2* __restrict__ v2,
                        const __half2* __restrict__ T2,
                        const int* __restrict__ src, const int* __restrict__ dst,
                        const float* __restrict__ dist, float* __restrict__ sums) {
    int cp = threadIdx.x & 63, slot = threadIdx.x >> 6;
    float sx = 0.f, sy = 0.f, qx = 0.f, qy = 0.f;
    for (int e = blockIdx.x * 4 + slot; e < EE; e += gridDim.x * 4) {
        int di = dst[e], si = src[e];
        float t = dist[e] * (4095.0f / 6.0f);
        int j = (int)t; j = min(j, TS - 2);
        float f = t - (float)j;
        float2 uu = __half22float2(u2[(size_t)di * 64 + cp]);
        float2 vv = __half22float2(v2[(size_t)si * 64 + cp]);
        float2 t0 = __half22float2(T2[(size_t)j * 64 + cp]);
        float2 t1 = __half22float2(T2[(size_t)(j + 1) * 64 + cp]);
        float z0 = uu.x + vv.x + t0.x + (t1.x - t0.x) * f;
        float z1 = uu.y + vv.y + t0.y + (t1.y - t0.y) * f;
        sx += z0; sy += z1; qx += z0 * z0; qy += z1 * z1;
    }
    __shared__ float red[4][64][4];
    red[slot][cp][0] = sx; red[slot][cp][1] = sy;
    red[slot][cp][2] = qx; red[slot][cp][3] = qy;
    __syncthreads();
    if (slot == 0) {
        for (int r = 1; r < 4; r++) {
            sx += red[r][cp][0]; sy += red[r][cp][1];
            qx += red[r][cp][2]; qy += red[r][cp][3];
        }
        atomicAdd(&sums[2 * cp], sx);
        atomicAdd(&sums[2 * cp + 1], sy);
        atomicAdd(&sums[128 + 2 * cp], qx);
        atomicAdd(&sums[128 + 2 * cp + 1], qy);
    }
}

// fold BN into A,B; zero sums for next layer
__global__ void k_finalize(float* __restrict__ sums, const float* __restrict__ bn_g,
                           const float* __restrict__ bn_b, int l, float* __restrict__ AB) {
    int c = threadIdx.x; // 128
    float mu = sums[c] * (1.0f / EE);
    float ms = sums[128 + c] * (1.0f / EE);
    float var = ms - mu * mu;
    float rstd = rsqrtf(var + EPS);
    float A = rstd * bn_g[l * 128 + c];
    float B = bn_b[l * 128 + c] - mu * A;
    AB[c] = A; AB[128 + c] = B;
    sums[c] = 0.f; sums[128 + c] = 0.f;
}

// pass B: recompute z, BN, m = sigmoid*softplus, CSR aggregate, LN+residual+softplus
__global__ void __launch_bounds__(256) k_conv_agg(
    const __half* __restrict__ u, const __half* __restrict__ v, const __half* __restrict__ T,
    const int* __restrict__ src, const float* __restrict__ dist,
    const int* __restrict__ rp, const int* __restrict__ perm,
    const float* __restrict__ AB, const float* __restrict__ lng, const float* __restrict__ lnb,
    int l, const float* __restrict__ xin, float* __restrict__ xout) {
    int i = blockIdx.x;
    int c = threadIdx.x & 63, slot = threadIdx.x >> 6;
    float uc  = __half2float(u[(size_t)i * 128 + c]);
    float uc2 = __half2float(u[(size_t)i * 128 + c + 64]);
    float A1 = AB[c], A2 = AB[c + 64], B1 = AB[128 + c], B2 = AB[128 + c + 64];
    float acc = 0.f;
    int rs = rp[i], re = rp[i + 1];
    for (int idx = rs + slot; idx < re; idx += 4) {
        int e = perm[idx];
        int si = src[e];
        float t = dist[e] * (4095.0f / 6.0f);
        int j = (int)t; j = min(j, TS - 2);
        float f = t - (float)j;
        const __half* t0p = T + (size_t)j * 128;
        float t0a = __half2float(t0p[c]),      t1a = __half2float(t0p[128 + c]);
        float t0b = __half2float(t0p[64 + c]), t1b = __half2float(t0p[192 + c]);
        float z1 = uc  + __half2float(v[(size_t)si * 128 + c])      + t0a + (t1a - t0a) * f;
        float z2 = uc2 + __half2float(v[(size_t)si * 128 + c + 64]) + t0b + (t1b - t0b) * f;
        float zb1 = z1 * A1 + B1;
        float zb2 = z2 * A2 + B2;
        float sg = 1.0f / (1.0f + __expf(-zb1));
        acc += sg * softplus_f(zb2);
    }
    __shared__ float red[4][64];
    red[slot][c] = acc;
    __syncthreads();
    if (slot == 0) {
        float a = red[0][c] + red[1][c] + red[2][c] + red[3][c];
        float s = a;
#pragma unroll
        for (int off = 32; off; off >>= 1) s += __shfl_xor(s, off, 64);
        float mean = s * (1.0f / 64.0f);
        float e0 = a - mean;
        float vv = e0 * e0;
#pragma unroll
        for (int off = 32; off; off >>= 1) vv += __shfl_xor(vv, off, 64);
        float var = vv * (1.0f / 64.0f);
        float h = e0 * rsqrtf(var + EPS) * lng[l * 64 + c] + lnb[l * 64 + c];
        float xn = h + xin[(size_t)i * 64 + c];
        xout[(size_t)i * 64 + c] = softplus_f(xn);
    }
}

__global__ void k_pool(const float* __restrict__ x, const int* __restrict__ batch,
                       float* __restrict__ mols, float* __restrict__ cnt) {
    int c = threadIdx.x & 63, nl = threadIdx.x >> 6;
    int n = blockIdx.x * 4 + nl;
    if (n >= NN) return;
    int g = batch[n];
    atomicAdd(&mols[g * 64 + c], x[(size_t)n * 64 + c]);
    if (c == 0) atomicAdd(&cnt[g], 1.0f);
}

__global__ void k_mlp(const float* __restrict__ mols, const float* __restrict__ cnt,
                      const float* __restrict__ fc1W, const float* __restrict__ fc1b,
                      const float* __restrict__ fcsW, const float* __restrict__ fcsb,
                      const float* __restrict__ outW, const float* __restrict__ outb,
                      float* __restrict__ y) {
    int g = blockIdx.x, t = threadIdx.x; // 128 threads
    __shared__ float m[64];
    __shared__ float h[128];
    __shared__ float rbuf[128];
    if (t < 64) {
        float cc = fmaxf(cnt[g], 1.0f);
        m[t] = mols[g * 64 + t] / cc;
    }
    __syncthreads();
    float a = fc1b[t];
#pragma unroll 4
    for (int k = 0; k < 64; k++) a += m[k] * fc1W[k * 128 + t];
    h[t] = softplus_f(a);
    __syncthreads();
    for (int i = 0; i < 3; i++) {
        float b = fcsb[i * 128 + t];
#pragma unroll 4
        for (int k = 0; k < 128; k++) b += h[k] * fcsW[((size_t)i * 128 + k) * 128 + t];
        __syncthreads();
        h[t] = softplus_f(b);
        __syncthreads();
    }
    rbuf[t] = h[t] * outW[t];
    __syncthreads();
    if (t < 64) {
        float s2 = rbuf[t] + rbuf[t + 64];
#pragma unroll
        for (int off = 32; off; off >>= 1) s2 += __shfl_xor(s2, off, 64);
        if (t == 0) y[g] = s2 + outb[0];
    }
}

extern "C" void kernel_launch(void* const* d_in, const int* in_sizes, int n_in,
                              void* d_out, int out_size, void* d_ws, size_t ws_size,
                              hipStream_t stream) {
    const int*   an    = (const int*)d_in[0];
    const int*   nbr   = (const int*)d_in[1];
    const float* dist  = (const float*)d_in[2];
    const int*   batch = (const int*)d_in[3];
    const float* emb   = (const float*)d_in[4];
    const float* nucW  = (const float*)d_in[5];
    const float* nucB  = (const float*)d_in[6];
    const float* convW = (const float*)d_in[7];
    const float* convB = (const float*)d_in[8];
    const float* bng   = (const float*)d_in[9];
    const float* bnb   = (const float*)d_in[10];
    const float* lng   = (const float*)d_in[11];
    const float* lnb   = (const float*)d_in[12];
    const float* fc1W  = (const float*)d_in[13];
    const float* fc1b  = (const float*)d_in[14];
    const float* fcsW  = (const float*)d_in[15];
    const float* fcsb  = (const float*)d_in[16];
    const float* outW  = (const float*)d_in[17];
    const float* outb  = (const float*)d_in[18];
    const int* srcI = nbr;
    const int* dstI = nbr + EE;

    char* base = (char*)d_ws;
    size_t off = 0;
    auto alloc = [&](size_t b) { size_t r = off; off += (b + 255) & ~(size_t)255; return r; };
    float*  gtab   = (float*)(base + alloc((size_t)TS * 100 * 4));
    __half* Tall   = (__half*)(base + alloc((size_t)6 * TS * 128 * 2));
    float*  x0     = (float*)(base + alloc((size_t)NN * 64 * 4));
    float*  x1     = (float*)(base + alloc((size_t)NN * 64 * 4));
    __half* u      = (__half*)(base + alloc((size_t)NN * 128 * 2));
    __half* v      = (__half*)(base + alloc((size_t)NN * 128 * 2));
    float*  sums   = (float*)(base + alloc(256 * 4));
    float*  AB     = (float*)(base + alloc(256 * 4));
    int*    counts = (int*)(base + alloc((size_t)NN * 4));
    int*    cursor = (int*)(base + alloc((size_t)NN * 4));
    int*    rp     = (int*)(base + alloc((size_t)(NN + 1) * 4));
    int*    perm   = (int*)(base + alloc((size_t)EE * 4));
    float*  mols   = (float*)(base + alloc((size_t)GG * 64 * 4));
    float*  cnt    = (float*)(base + alloc((size_t)GG * 4));

    hipMemsetAsync(counts, 0, (size_t)NN * 4, stream);
    hipMemsetAsync(cursor, 0, (size_t)NN * 4, stream);
    hipMemsetAsync(sums, 0, 256 * 4, stream);
    hipMemsetAsync(mols, 0, (size_t)GG * 64 * 4, stream);
    hipMemsetAsync(cnt, 0, (size_t)GG * 4, stream);

    k_gtab<<<(TS * 100 + 255) / 256, 256, 0, stream>>>(gtab);
    k_build_T<<<dim3(TS, 6), 128, 0, stream>>>(gtab, convW, convB, Tall);
    k_embed<<<(NN + 3) / 4, 256, 0, stream>>>(an, emb, nucW, nucB, x0);
    k_hist<<<(EE + 255) / 256, 256, 0, stream>>>(dstI, counts);
    k_scan<<<1, 1024, 0, stream>>>(counts, rp);
    k_scatter<<<(EE + 255) / 256, 256, 0, stream>>>(dstI, rp, cursor, perm);

    float* xin = x0;
    float* xout = x1;
    for (int l = 0; l < 6; l++) {
        k_uv<<<(NN + 3) / 4, 256, 0, stream>>>(xin, convW, l, u, v);
        const __half* Tl = Tall + (size_t)l * TS * 128;
        k_stats<<<1024, 256, 0, stream>>>((const __half2*)u, (const __half2*)v,
                                          (const __half2*)Tl, srcI, dstI, dist, sums);
        k_finalize<<<1, 128, 0, stream>>>(sums, bng, bnb, l, AB);
        k_conv_agg<<<NN, 256, 0, stream>>>(u, v, Tl, srcI, dist, rp, perm,
                                           AB, lng, lnb, l, xin, xout);
        float* tmp = xin; xin = xout; xout = tmp;
    }
    k_pool<<<(NN + 3) / 4, 256, 0, stream>>>(xin, batch, mols, cnt);
    k_mlp<<<GG, 128, 0, stream>>>(mols, cnt, fc1W, fc1b, fcsW, fcsb, outW, outb, (float*)d_out);
}